// Round 8
// baseline (255.770 us; speedup 1.0000x reference)
//
#include <hip/hip_runtime.h>
#include <hip/hip_bf16.h>
#include <math.h>

// CrossEntropy3d OHEM: predict (n=2, c=12, d=64, h=128, w=128) f32,
// target (2,64,128,128) int32. Class stride = d*h*w = 1<<20 floats (4 MB).
//
// R8: (a) REAL per-wave MLP test: all 12 float4 class-loads live at once in
// registers before any use; __launch_bounds__(256,4) = 128-VGPR budget
// (~75 needed). R3/R4 showed VGPR_Count=32 -> compiler recycled 2-3 load
// regs with waitcnts between => MLP never actually tested until now.
// (b) 2 dispatches only: 64B memset + fused main. Rare OHEM path
// (threshold > 0.9) handled entirely inside the last arriving block with an
// LDS histogram + rescan (never taken for the bench input; correctness
// fallback only).
// Fixed harness overhead in timed window: ws poison ~59us + d_in restore
// ~33us => ~95us floor.

#define IGNORE_LABEL 255
#define MIN_KEPT 10000u

constexpr int   C         = 12;
constexpr int   PIX_SHIFT = 20;              // d*h*w = 1<<20
constexpr int   PIX_MASK  = (1 << PIX_SHIFT) - 1;
constexpr int   NBINS     = 2048;            // histogram over (0.9, 1.0]
constexpr float BIN_SCALE = (float)NBINS / 0.1f;

// ws layout: [0..63] header (done counter at offset 0); [64..] uint4/block
// partials (sle, sva as float bits; cle, cva). Partials are written
// unconditionally by every block -> no zeroing needed; only the 64B header
// is memset per launch.

__device__ inline float wave_reduce_f(float v) {
    #pragma unroll
    for (int o = 32; o > 0; o >>= 1) v += __shfl_down(v, o, 64);
    return v;
}
__device__ inline unsigned int wave_reduce_u(unsigned int v) {
    #pragma unroll
    for (int o = 32; o > 0; o >>= 1) v += __shfl_down(v, o, 64);
    return v;
}

__global__ __launch_bounds__(256, 4) void fused_kernel(
        const float* __restrict__ pred, const int* __restrict__ tgt,
        unsigned int* __restrict__ done, uint4* __restrict__ partials,
        float* __restrict__ out, int npix_q) {
    const int tid = blockIdx.x * blockDim.x + threadIdx.x;

    float        my_sle = 0.0f, my_sva = 0.0f;
    unsigned int my_cle = 0u,   my_cva = 0u;

    if (tid < npix_q) {
        const int p0 = tid << 2;
        const float* base = pred +
            (((size_t)(p0 >> PIX_SHIFT) * C) << PIX_SHIFT) + (p0 & PIX_MASK);

        // ALL class loads issued before any consumer: 12 float4 live at once.
        float4 v[C];
        #pragma unroll
        for (int ci = 0; ci < C; ++ci)
            v[ci] = *(const float4*)(base + ((size_t)ci << PIX_SHIFT));
        const int4 li = *(const int4*)(tgt + p0);
        const int lab[4] = {li.x, li.y, li.z, li.w};

        float s[4]     = {0.0f, 0.0f, 0.0f, 0.0f};
        float l_lab[4] = {0.0f, 0.0f, 0.0f, 0.0f};
        #pragma unroll
        for (int ci = 0; ci < C; ++ci) {
            const float vv[4] = {v[ci].x, v[ci].y, v[ci].z, v[ci].w};
            #pragma unroll
            for (int j = 0; j < 4; ++j) {
                s[j] += __expf(vv[j]);
                if (lab[j] == ci) l_lab[j] = vv[j];
            }
        }
        #pragma unroll
        for (int j = 0; j < 4; ++j) {
            const float ls   = __logf(s[j]);
            const float nll  = ls - l_lab[j];
            const float prob = __expf(l_lab[j] - ls);
            if (lab[j] != IGNORE_LABEL) {
                my_cva += 1u;
                my_sva += nll;
                if (prob <= 0.9f) { my_cle += 1u; my_sle += nll; }
                // prob > 0.9 handled (if ever needed) by last-block rescan
            }
        }
    }

    // ---- block reduction -> one partial store per block ----
    __shared__ float        s_le[4], s_va[4];
    __shared__ unsigned int s_cle[4], s_cva[4];
    __shared__ int          s_last;
    const int wid = threadIdx.x >> 6, lane = threadIdx.x & 63;
    {
        const float        r_le = wave_reduce_f(my_sle);
        const float        r_va = wave_reduce_f(my_sva);
        const unsigned int r_cl = wave_reduce_u(my_cle);
        const unsigned int r_cv = wave_reduce_u(my_cva);
        if (lane == 0) { s_le[wid] = r_le; s_va[wid] = r_va; s_cle[wid] = r_cl; s_cva[wid] = r_cv; }
    }
    __syncthreads();
    if (threadIdx.x == 0) {
        uint4 p;
        p.x = __float_as_uint(s_le[0] + s_le[1] + s_le[2] + s_le[3]);
        p.y = __float_as_uint(s_va[0] + s_va[1] + s_va[2] + s_va[3]);
        p.z = s_cle[0] + s_cle[1] + s_cle[2] + s_cle[3];
        p.w = s_cva[0] + s_cva[1] + s_cva[2] + s_cva[3];
        partials[blockIdx.x] = p;          // fire-and-forget, distinct lines
        __threadfence();                   // release: partial before arrival
        const unsigned int prev = atomicAdd(done, 1u);
        s_last = (prev == gridDim.x - 1u);
    }
    __syncthreads();
    if (!s_last) return;

    // ================= last arriving block: global finalize =================
    __threadfence();                       // acquire: see all partials
    double       sle = 0.0, sva = 0.0;
    unsigned int cle = 0u,  cva = 0u;
    for (int i = threadIdx.x; i < gridDim.x; i += blockDim.x) {
        const uint4 p = partials[i];
        sle += (double)__uint_as_float(p.x);
        sva += (double)__uint_as_float(p.y);
        cle += p.z;
        cva += p.w;
    }
    __shared__ double d_le[4], d_va[4];
    {
        double rs = sle, rv = sva;
        #pragma unroll
        for (int o = 32; o > 0; o >>= 1) { rs += __shfl_down(rs, o, 64); rv += __shfl_down(rv, o, 64); }
        const unsigned int rcl = wave_reduce_u(cle);
        const unsigned int rcv = wave_reduce_u(cva);
        if (lane == 0) { d_le[wid] = rs; d_va[wid] = rv; s_cle[wid] = rcl; s_cva[wid] = rcv; }
    }
    __syncthreads();

    __shared__ double       sh_sle, sh_sva;
    __shared__ unsigned int sh_cle, sh_cva;
    __shared__ int          sh_path;       // 0 = done, 1 = rare path
    if (threadIdx.x == 0) {
        double       t_sle = 0.0, t_sva = 0.0;
        unsigned int t_cle = 0u,  t_cva = 0u;
        #pragma unroll
        for (int i = 0; i < 4; ++i) {
            t_sle += d_le[i]; t_sva += d_va[i]; t_cle += s_cle[i]; t_cva += s_cva[i];
        }
        sh_sle = t_sle; sh_sva = t_sva; sh_cle = t_cle; sh_cva = t_cva;
        const unsigned int nv = t_cva;
        const unsigned int k  = nv < MIN_KEPT ? nv : MIN_KEPT;
        if (MIN_KEPT >= nv) {                 // keep all valid
            out[0] = (float)(t_sva / (double)(nv > 0u ? nv : 1u));
            sh_path = 0;
        } else if (t_cle >= k) {              // threshold = 0.9 (normal path)
            out[0] = (float)(t_sle / (double)(t_cle > 0u ? t_cle : 1u));
            sh_path = 0;
        } else {
            sh_path = 1;                      // kth prob in (0.9,1]: rare
        }
    }
    __syncthreads();
    if (sh_path == 0) return;

    // ---- RARE path (never taken for bench input): this block alone builds
    //      an LDS histogram of probs in (0.9,1], derives a (bin-edge)
    //      threshold, rescans for the kept sum. ----
    __shared__ unsigned int hist[NBINS];
    for (int i = threadIdx.x; i < NBINS; i += blockDim.x) hist[i] = 0u;
    __syncthreads();

    for (int t = threadIdx.x; t < npix_q; t += blockDim.x) {
        const int p0 = t << 2;
        const float* base = pred +
            (((size_t)(p0 >> PIX_SHIFT) * C) << PIX_SHIFT) + (p0 & PIX_MASK);
        const int4 li = *(const int4*)(tgt + p0);
        const int lab[4] = {li.x, li.y, li.z, li.w};
        float s[4] = {0,0,0,0}, l_lab[4] = {0,0,0,0};
        #pragma unroll
        for (int ci = 0; ci < C; ++ci) {
            const float4 v = *(const float4*)(base + ((size_t)ci << PIX_SHIFT));
            const float vv[4] = {v.x, v.y, v.z, v.w};
            #pragma unroll
            for (int j = 0; j < 4; ++j) {
                s[j] += __expf(vv[j]);
                if (lab[j] == ci) l_lab[j] = vv[j];
            }
        }
        #pragma unroll
        for (int j = 0; j < 4; ++j) {
            const float prob = __expf(l_lab[j] - __logf(s[j]));
            if (lab[j] != IGNORE_LABEL && prob > 0.9f) {
                int b = (int)((prob - 0.9f) * BIN_SCALE);
                b = b < 0 ? 0 : (b >= NBINS - 1 ? NBINS - 1 : b);
                atomicAdd(&hist[b], 1u);
            }
        }
    }
    __syncthreads();

    __shared__ float sh_th;
    if (threadIdx.x == 0) {
        const unsigned int nv = sh_cva;
        const unsigned int k  = nv < MIN_KEPT ? nv : MIN_KEPT;
        unsigned int cum = sh_cle;
        int b = NBINS - 1;
        for (int i = 0; i < NBINS; ++i) {
            cum += hist[i];
            if (cum >= k) { b = i; break; }
        }
        sh_th = 0.9f + (float)(b + 1) * (0.1f / (float)NBINS);
    }
    __syncthreads();
    const float th = sh_th;

    float        my_s = 0.0f;
    unsigned int my_c = 0u;
    for (int t = threadIdx.x; t < npix_q; t += blockDim.x) {
        const int p0 = t << 2;
        const float* base = pred +
            (((size_t)(p0 >> PIX_SHIFT) * C) << PIX_SHIFT) + (p0 & PIX_MASK);
        const int4 li = *(const int4*)(tgt + p0);
        const int lab[4] = {li.x, li.y, li.z, li.w};
        float s[4] = {0,0,0,0}, l_lab[4] = {0,0,0,0};
        #pragma unroll
        for (int ci = 0; ci < C; ++ci) {
            const float4 v = *(const float4*)(base + ((size_t)ci << PIX_SHIFT));
            const float vv[4] = {v.x, v.y, v.z, v.w};
            #pragma unroll
            for (int j = 0; j < 4; ++j) {
                s[j] += __expf(vv[j]);
                if (lab[j] == ci) l_lab[j] = vv[j];
            }
        }
        #pragma unroll
        for (int j = 0; j < 4; ++j) {
            const float ls   = __logf(s[j]);
            const float nll  = ls - l_lab[j];
            const float prob = __expf(l_lab[j] - ls);
            if (lab[j] != IGNORE_LABEL && prob <= th) { my_c += 1u; my_s += nll; }
        }
    }
    {
        const float        r_s = wave_reduce_f(my_s);
        const unsigned int r_c = wave_reduce_u(my_c);
        if (lane == 0) { s_le[wid] = r_s; s_cle[wid] = r_c; }
    }
    __syncthreads();
    if (threadIdx.x == 0) {
        const float        t_s = s_le[0] + s_le[1] + s_le[2] + s_le[3];
        const unsigned int t_c = s_cle[0] + s_cle[1] + s_cle[2] + s_cle[3];
        out[0] = (float)((double)t_s / (double)(t_c > 0u ? t_c : 1u));
    }
}

extern "C" void kernel_launch(void* const* d_in, const int* in_sizes, int n_in,
                              void* d_out, int out_size, void* d_ws, size_t ws_size,
                              hipStream_t stream) {
    const float*  pred = (const float*)d_in[0];
    const int*    tgt  = (const int*)d_in[1];
    float*        out  = (float*)d_out;
    unsigned int* done = (unsigned int*)d_ws;
    uint4*        partials = (uint4*)((char*)d_ws + 64);

    const int npix   = in_sizes[1];            // 2,097,152
    const int npix_q = npix >> 2;              // 524,288 quads
    const int blocks = (npix_q + 255) / 256;   // 2048 blocks of 256 thr

    hipMemsetAsync(d_ws, 0, 64, stream);       // zero arrival counter only
    fused_kernel<<<blocks, 256, 0, stream>>>(pred, tgt, done, partials, out, npix_q);
}

// Round 9
// 157.914 us; speedup vs baseline: 1.6197x; 1.6197x over previous
//
#include <hip/hip_runtime.h>
#include <hip/hip_bf16.h>
#include <math.h>

// CrossEntropy3d OHEM: predict (n=2, c=12, d=64, h=128, w=128) f32,
// target (2,64,128,128) int32. Class stride = d*h*w = 1<<20 floats (4 MB).
//
// R9: stream-dwell experiment on the R4 structure (best known, 161.5us).
// Evidence: R6 (nt, latency up -> dur up, LLC-resident replay same dur) =
// latency/issue-bound, not BW; R5 (2x waves) / R7 (LDS staging) / R8 (wide
// live loads) all neutral-or-worse. Untested axis: per-class contiguous
// chunk per thread (dwell per 4MB-strided stream before switching).
// Here: 8 px/thread (32B/class chunk, wave dwell 2KB/class), loop-carried
// E[8]/l_lab[8]/lab[8] so the allocator cannot sink or batch them away.
// __launch_bounds__(256,4) = 128 VGPR cap (~56 needed).
// Fixed harness overhead in timed window: ws poison ~59us + d_in restore
// ~33us => ~95us floor.

#define IGNORE_LABEL 255
#define MIN_KEPT 10000u

constexpr int   C         = 12;
constexpr int   PIX_SHIFT = 20;              // d*h*w = 1<<20
constexpr int   PIX_MASK  = (1 << PIX_SHIFT) - 1;
constexpr int   NBINS     = 2048;            // histogram over (0.9, 1.0]
constexpr float BIN_SCALE = (float)NBINS / 0.1f;

struct Ws {
    double       sum_p3;     // fallback sum (atomics; rare path only)
    unsigned int cnt_p3;
    unsigned int flag;       // 1 => fallback must run
    float        threshold;  // fallback threshold
    unsigned int done;       // main-pass arrival counter (unused here)
    unsigned int done2;      // fallback arrival counter
    unsigned int pad[9];     // pad to 64 B
    unsigned int hist[NBINS];
};
// uint4 per main block (sle, sva as float bits; cle, cva) right after Ws.

__device__ inline float wave_reduce_f(float v) {
    #pragma unroll
    for (int o = 32; o > 0; o >>= 1) v += __shfl_down(v, o, 64);
    return v;
}
__device__ inline unsigned int wave_reduce_u(unsigned int v) {
    #pragma unroll
    for (int o = 32; o > 0; o >>= 1) v += __shfl_down(v, o, 64);
    return v;
}
__device__ inline double wave_reduce_d(double v) {
    #pragma unroll
    for (int o = 32; o > 0; o >>= 1) v += __shfl_down(v, o, 64);
    return v;
}

__global__ __launch_bounds__(256, 4) void main_pass_kernel(
        const float* __restrict__ pred, const int* __restrict__ tgt,
        Ws* __restrict__ ws, uint4* __restrict__ partials, int npix) {
    const int tid = blockIdx.x * blockDim.x + threadIdx.x;

    float        my_sle = 0.0f, my_sva = 0.0f;
    unsigned int my_cle = 0u,   my_cva = 0u;

    const int p0 = tid << 3;                  // 8 consecutive pixels
    if (p0 < npix) {
        const float* base = pred +
            (((size_t)(p0 >> PIX_SHIFT) * C) << PIX_SHIFT) + (p0 & PIX_MASK);
        const int4 la = *(const int4*)(tgt + p0);
        const int4 lb = *(const int4*)(tgt + p0 + 4);
        const int lab[8] = {la.x, la.y, la.z, la.w, lb.x, lb.y, lb.z, lb.w};

        // loop-carried per-pixel state: exp-sum + label logit (cannot be sunk)
        float E[8]  = {0,0,0,0,0,0,0,0};
        float ll[8] = {0,0,0,0,0,0,0,0};
        #pragma unroll
        for (int ci = 0; ci < C; ++ci) {
            const float* csrc = base + ((size_t)ci << PIX_SHIFT);
            const float4 v0 = *(const float4*)(csrc);
            const float4 v1 = *(const float4*)(csrc + 4);
            const float vv[8] = {v0.x, v0.y, v0.z, v0.w, v1.x, v1.y, v1.z, v1.w};
            #pragma unroll
            for (int j = 0; j < 8; ++j) {
                E[j] += __expf(vv[j]);
                if (lab[j] == ci) ll[j] = vv[j];
            }
        }
        #pragma unroll
        for (int j = 0; j < 8; ++j) {
            const float ls   = __logf(E[j]);
            const float nll  = ls - ll[j];
            const float prob = __expf(ll[j] - ls);
            if (lab[j] != IGNORE_LABEL) {
                my_cva += 1u;
                my_sva += nll;
                if (prob <= 0.9f) {
                    my_cle += 1u;
                    my_sle += nll;
                } else {
                    int b = (int)((prob - 0.9f) * BIN_SCALE);
                    b = b < 0 ? 0 : (b >= NBINS - 1 ? NBINS - 1 : b);
                    atomicAdd(&ws->hist[b], 1u);   // rare
                }
            }
        }
    }

    __shared__ float        s_le[4], s_va[4];
    __shared__ unsigned int s_cle[4], s_cva[4];
    const int wid = threadIdx.x >> 6, lane = threadIdx.x & 63;
    const float        r_le = wave_reduce_f(my_sle);
    const float        r_va = wave_reduce_f(my_sva);
    const unsigned int r_cl = wave_reduce_u(my_cle);
    const unsigned int r_cv = wave_reduce_u(my_cva);
    if (lane == 0) { s_le[wid] = r_le; s_va[wid] = r_va; s_cle[wid] = r_cl; s_cva[wid] = r_cv; }
    __syncthreads();
    if (threadIdx.x == 0) {
        uint4 p;
        p.x = __float_as_uint(s_le[0] + s_le[1] + s_le[2] + s_le[3]);
        p.y = __float_as_uint(s_va[0] + s_va[1] + s_va[2] + s_va[3]);
        p.z = s_cle[0] + s_cle[1] + s_cle[2] + s_cle[3];
        p.w = s_cva[0] + s_cva[1] + s_cva[2] + s_cva[3];
        partials[blockIdx.x] = p;   // fire-and-forget, distinct lines
    }
}

__global__ __launch_bounds__(1024) void reduce_finalize_kernel(
        Ws* __restrict__ ws, const uint4* __restrict__ partials,
        int nblocks, float* __restrict__ out) {
    double       sle = 0.0, sva = 0.0;
    unsigned int cle = 0u,  cva = 0u;
    for (int i = threadIdx.x; i < nblocks; i += 1024) {
        const uint4 p = partials[i];
        sle += (double)__uint_as_float(p.x);
        sva += (double)__uint_as_float(p.y);
        cle += p.z;
        cva += p.w;
    }
    __shared__ double       d_le[16], d_va[16];
    __shared__ unsigned int u_le[16], u_va[16];
    const int wid = threadIdx.x >> 6, lane = threadIdx.x & 63;
    const double       r_sle = wave_reduce_d(sle);
    const double       r_sva = wave_reduce_d(sva);
    const unsigned int r_cle = wave_reduce_u(cle);
    const unsigned int r_cva = wave_reduce_u(cva);
    if (lane == 0) { d_le[wid] = r_sle; d_va[wid] = r_sva; u_le[wid] = r_cle; u_va[wid] = r_cva; }
    __syncthreads();
    if (threadIdx.x == 0) {
        double       t_sle = 0.0, t_sva = 0.0;
        unsigned int t_cle = 0u,  t_cva = 0u;
        #pragma unroll
        for (int i = 0; i < 16; ++i) {
            t_sle += d_le[i]; t_sva += d_va[i]; t_cle += u_le[i]; t_cva += u_va[i];
        }
        const unsigned int nv = t_cva;
        const unsigned int k  = nv < MIN_KEPT ? nv : MIN_KEPT;
        if (MIN_KEPT >= nv) {                 // keep all valid
            out[0] = (float)(t_sva / (double)(nv > 0u ? nv : 1u));
            ws->flag = 0u;
        } else if (t_cle >= k) {              // threshold = 0.9 (normal path)
            out[0] = (float)(t_sle / (double)(t_cle > 0u ? t_cle : 1u));
            ws->flag = 0u;
        } else {
            unsigned int cum = t_cle;         // kth prob in (0.9, 1]
            int b = NBINS - 1;
            for (int i = 0; i < NBINS; ++i) {
                cum += ws->hist[i];
                if (cum >= k) { b = i; break; }
            }
            ws->threshold = 0.9f + (float)(b + 1) * (0.1f / (float)NBINS);
            ws->flag = 1u;
            out[0] = 0.0f;                    // overwritten by fallback
        }
    }
}

// Rare path: full recompute with histogram-derived (conservative) threshold;
// finalize fused via last-block arrival counter.
__global__ __launch_bounds__(256) void fallback_kernel(
        const float* __restrict__ pred, const int* __restrict__ tgt,
        Ws* __restrict__ ws, float* __restrict__ out, int npix_q) {
    if (ws->flag == 0u) return;   // normal case: exit immediately
    const float th = ws->threshold;
    const int stride = gridDim.x * blockDim.x;

    float        my_s = 0.0f;
    unsigned int my_c = 0u;
    for (int t = blockIdx.x * blockDim.x + threadIdx.x; t < npix_q; t += stride) {
        const int p0 = t << 2;
        const float* base = pred +
            (((size_t)(p0 >> PIX_SHIFT) * C) << PIX_SHIFT) + (p0 & PIX_MASK);
        const int4 li = *(const int4*)(tgt + p0);
        const int lab[4] = {li.x, li.y, li.z, li.w};
        float s[4] = {0,0,0,0}, l_lab[4] = {0,0,0,0};
        #pragma unroll
        for (int ci = 0; ci < C; ++ci) {
            const float4 v = *(const float4*)(base + ((size_t)ci << PIX_SHIFT));
            const float vv[4] = {v.x, v.y, v.z, v.w};
            #pragma unroll
            for (int j = 0; j < 4; ++j) {
                s[j] += __expf(vv[j]);
                if (lab[j] == ci) l_lab[j] = vv[j];
            }
        }
        #pragma unroll
        for (int j = 0; j < 4; ++j) {
            const float ls   = __logf(s[j]);
            const float nll  = ls - l_lab[j];
            const float prob = __expf(l_lab[j] - ls);
            if (lab[j] != IGNORE_LABEL && prob <= th) { my_c += 1u; my_s += nll; }
        }
    }
    __shared__ float        s_s[4];
    __shared__ unsigned int s_c[4];
    const int wid = threadIdx.x >> 6, lane = threadIdx.x & 63;
    const float        r_s = wave_reduce_f(my_s);
    const unsigned int r_c = wave_reduce_u(my_c);
    if (lane == 0) { s_s[wid] = r_s; s_c[wid] = r_c; }
    __syncthreads();
    if (threadIdx.x == 0) {
        const float        t_s = s_s[0] + s_s[1] + s_s[2] + s_s[3];
        const unsigned int t_c = s_c[0] + s_c[1] + s_c[2] + s_c[3];
        if (t_s != 0.0f) atomicAdd(&ws->sum_p3, (double)t_s);
        if (t_c)         atomicAdd(&ws->cnt_p3, t_c);
        __threadfence();
        const unsigned int prev = atomicAdd(&ws->done2, 1u);
        if (prev == gridDim.x - 1u) {          // last block finalizes
            const unsigned int cnt = ws->cnt_p3;
            out[0] = (float)(ws->sum_p3 / (double)(cnt > 0u ? cnt : 1u));
        }
    }
}

extern "C" void kernel_launch(void* const* d_in, const int* in_sizes, int n_in,
                              void* d_out, int out_size, void* d_ws, size_t ws_size,
                              hipStream_t stream) {
    const float* pred = (const float*)d_in[0];
    const int*   tgt  = (const int*)d_in[1];
    float*       out  = (float*)d_out;
    Ws*          ws   = (Ws*)d_ws;
    uint4*       partials = (uint4*)((char*)d_ws + sizeof(Ws));

    const int npix   = in_sizes[1];            // 2,097,152
    const int npix_q = npix >> 2;
    const int blocks = (npix / 8 + 255) / 256; // 1024 blocks of 256 thr

    hipMemsetAsync(d_ws, 0, sizeof(Ws), stream);
    main_pass_kernel<<<blocks, 256, 0, stream>>>(pred, tgt, ws, partials, npix);
    reduce_finalize_kernel<<<1, 1024, 0, stream>>>(ws, partials, blocks, out);
    fallback_kernel<<<128, 256, 0, stream>>>(pred, tgt, ws, out, npix_q);
}